// Round 2
// baseline (345.653 us; speedup 1.0000x reference)
//
#include <hip/hip_runtime.h>
#include <stdint.h>

// Problem constants (fixed by the reference)
#define C_IN   96
#define KIN    768      // 8*C
#define NOUT   192
#define MTILE  32       // tokens per block (= one (b,d,h) row, w=0..31)
#define LDK    772      // KIN + 4 bf16 pad -> row stride 1544 B (odd multiple of 8 B):
                        // phase-1 b64 writes hit all 16 bank-pairs (4-way = minimum);
                        // phase-3 b128 reads uniform over 32 banks.
#define EPS    1e-5f

typedef __bf16 bf16x8 __attribute__((ext_vector_type(8)));
typedef float  f32x4  __attribute__((ext_vector_type(4)));

static __device__ __forceinline__ unsigned int f2bf(float f) {
    union { float f; unsigned int u; } v; v.f = f;
    return (v.u + 0x7fffu + ((v.u >> 16) & 1u)) >> 16;   // RNE bf16, low 16 bits
}
static __device__ __forceinline__ float bf2f(unsigned int s) {
    union { unsigned int u; float f; } v; v.u = s << 16;
    return v.f;
}

// ---------------------------------------------------------------------------
// Prep: W'[o][c] = bf16(W[o][c]*ln_w[c]);  bias[o] = sum_c ln_b[c]*W[o][c];
//       S[o] = sum_c bf16(W'[o][c])   (colsum folds the mean subtraction:
//       out = rs*(y_raw . W'^T - mu*S) + bias  -- no normalize pass needed)
// ---------------------------------------------------------------------------
__global__ __launch_bounds__(256) void prep_kernel(
    const float* __restrict__ W, const float* __restrict__ lnw,
    const float* __restrict__ lnb, unsigned short* __restrict__ Wb,
    float* __restrict__ bias, float* __restrict__ Scol)
{
    int o = blockIdx.x;
    int tid = threadIdx.x;
    float bpart = 0.f, spart = 0.f;
    for (int c = tid; c < KIN; c += 256) {
        float w = W[(size_t)o * KIN + c];
        unsigned int rb = f2bf(w * lnw[c]);
        Wb[(size_t)o * KIN + c] = (unsigned short)rb;
        spart += bf2f(rb);
        bpart += w * lnb[c];
    }
    #pragma unroll
    for (int m = 32; m >= 1; m >>= 1) {
        bpart += __shfl_xor(bpart, m, 64);
        spart += __shfl_xor(spart, m, 64);
    }
    __shared__ float redb[4], reds[4];
    if ((tid & 63) == 0) { redb[tid >> 6] = bpart; reds[tid >> 6] = spart; }
    __syncthreads();
    if (tid == 0) {
        bias[o] = redb[0] + redb[1] + redb[2] + redb[3];
        Scol[o] = reds[0] + reds[1] + reds[2] + reds[3];
    }
}

// ---------------------------------------------------------------------------
// Fused gather + LayerNorm + GEMM (bf16 MFMA 16x16x32)
// Block: 256 threads (4 waves), 32 tokens. LDS caps us at 3 blocks/CU, so
// __launch_bounds__(256,3) frees the VGPR budget (~168) for load batching.
// ---------------------------------------------------------------------------
__global__ __launch_bounds__(256, 3) void merge_kernel(
    const float* __restrict__ x, const unsigned short* __restrict__ Wb,
    const float* __restrict__ bias, const float* __restrict__ Scol,
    float* __restrict__ out)
{
    __shared__ unsigned short ylds[MTILE * LDK];   // 49408 B
    __shared__ float muL[MTILE], rsL[MTILE];

    const int tid   = threadIdx.x;
    const int tbase = blockIdx.x * MTILE;
    const int bh = blockIdx.x;                 // = (b*32+d)*32 + h
    const int h  = bh & 31;
    const int d  = (bh >> 5) & 31;
    const int b  = bh >> 10;

    // ---- Phase 1: batched gather fp32 -> regs, then bf16 -> LDS + stats -----
    const int tk = tid >> 3;   // token in tile == w coordinate
    const int i  = tid & 7;    // sub-lane within token
    const float* base = x +
        ((size_t)((b * 64 + 2 * d) * 64 + 2 * h) * 64 + 2 * tk) * C_IN + i * 4;

    // voxel offsets (floats): (s0*4096 + s1*64 + s2)*96
    const int OFF[8] = {0, 96, 6144, 6240, 393216, 393312, 399360, 399456};

    float4 v[24];                       // 96 VGPRs of data: all 24 loads in flight
    #pragma unroll
    for (int g = 0; g < 8; ++g)
        #pragma unroll
        for (int jj = 0; jj < 3; ++jj)
            v[g * 3 + jj] = *(const float4*)(base + OFF[g] + jj * 32);

    float sum = 0.f, sq = 0.f;
    #pragma unroll
    for (int g = 0; g < 8; ++g) {
        #pragma unroll
        for (int jj = 0; jj < 3; ++jj) {
            float4 t = v[g * 3 + jj];
            sum += t.x + t.y + t.z + t.w;
            sq  += t.x * t.x + t.y * t.y + t.z * t.z + t.w * t.w;
            uint2 p;
            p.x = f2bf(t.x) | (f2bf(t.y) << 16);
            p.y = f2bf(t.z) | (f2bf(t.w) << 16);
            *(uint2*)&ylds[tk * LDK + g * 96 + (i + jj * 8) * 4] = p;
        }
    }
    #pragma unroll
    for (int m = 4; m >= 1; m >>= 1) {
        sum += __shfl_xor(sum, m, 8);
        sq  += __shfl_xor(sq,  m, 8);
    }
    if (i == 0) {
        float mean = sum * (1.f / 768.f);
        float var  = sq * (1.f / 768.f) - mean * mean;
        muL[tk] = mean;
        rsL[tk] = rsqrtf(var + EPS);
    }
    __syncthreads();

    // ---- Phase 2: GEMM on RAW bf16 y:  C = y . W'^T  ------------------------
    // wave wv handles N cols [wv*48, wv*48+48): 2 M-tiles x 3 N-tiles of 16x16
    const int wv    = tid >> 6;
    const int l     = tid & 63;
    const int l15   = l & 15;
    const int quad  = l >> 4;
    const int nbase = wv * 48;
    const int koff  = quad * 8;

    f32x4 acc[2][3];
    #pragma unroll
    for (int mt = 0; mt < 2; ++mt)
        #pragma unroll
        for (int nt = 0; nt < 3; ++nt)
            acc[mt][nt] = (f32x4){0.f, 0.f, 0.f, 0.f};

    const unsigned short* arow0 = &ylds[l15        * LDK + koff];
    const unsigned short* arow1 = &ylds[(16 + l15) * LDK + koff];
    const unsigned short* brow0 = Wb + (size_t)(nbase + l15) * KIN + koff;
    const unsigned short* brow1 = brow0 + 16 * KIN;
    const unsigned short* brow2 = brow0 + 32 * KIN;

    // depth-1 software pipeline: issue kk+1 loads before kk's MFMAs
    bf16x8 a0 = *(const bf16x8*)arow0;
    bf16x8 a1 = *(const bf16x8*)arow1;
    bf16x8 b0 = *(const bf16x8*)brow0;
    bf16x8 b1 = *(const bf16x8*)brow1;
    bf16x8 b2 = *(const bf16x8*)brow2;
    #pragma unroll
    for (int kk = 0; kk < 24; ++kk) {
        bf16x8 na0, na1, nb0, nb1, nb2;
        if (kk < 23) {
            const int k = (kk + 1) * 32;
            na0 = *(const bf16x8*)(arow0 + k);
            na1 = *(const bf16x8*)(arow1 + k);
            nb0 = *(const bf16x8*)(brow0 + k);
            nb1 = *(const bf16x8*)(brow1 + k);
            nb2 = *(const bf16x8*)(brow2 + k);
        }
        acc[0][0] = __builtin_amdgcn_mfma_f32_16x16x32_bf16(a0, b0, acc[0][0], 0, 0, 0);
        acc[0][1] = __builtin_amdgcn_mfma_f32_16x16x32_bf16(a0, b1, acc[0][1], 0, 0, 0);
        acc[0][2] = __builtin_amdgcn_mfma_f32_16x16x32_bf16(a0, b2, acc[0][2], 0, 0, 0);
        acc[1][0] = __builtin_amdgcn_mfma_f32_16x16x32_bf16(a1, b0, acc[1][0], 0, 0, 0);
        acc[1][1] = __builtin_amdgcn_mfma_f32_16x16x32_bf16(a1, b1, acc[1][1], 0, 0, 0);
        acc[1][2] = __builtin_amdgcn_mfma_f32_16x16x32_bf16(a1, b2, acc[1][2], 0, 0, 0);
        a0 = na0; a1 = na1; b0 = nb0; b1 = nb1; b2 = nb2;
    }

    // ---- Epilogue: out = rs*(dot - mu*S) + bias -----------------------------
    const float S0 = Scol[nbase + l15];
    const float S1 = Scol[nbase + 16 + l15];
    const float S2 = Scol[nbase + 32 + l15];
    const float c0 = bias[nbase + l15];
    const float c1 = bias[nbase + 16 + l15];
    const float c2 = bias[nbase + 32 + l15];
    #pragma unroll
    for (int mt = 0; mt < 2; ++mt) {
        #pragma unroll
        for (int r = 0; r < 4; ++r) {
            const int row = mt * 16 + quad * 4 + r;
            const float rs = rsL[row];
            const float rm = rs * muL[row];
            float* op = out + (size_t)(tbase + row) * NOUT + nbase + l15;
            op[0]  = rs * acc[mt][0][r] - rm * S0 + c0;
            op[16] = rs * acc[mt][1][r] - rm * S1 + c1;
            op[32] = rs * acc[mt][2][r] - rm * S2 + c2;
        }
    }
}

// ---------------------------------------------------------------------------
extern "C" void kernel_launch(void* const* d_in, const int* in_sizes, int n_in,
                              void* d_out, int out_size, void* d_ws, size_t ws_size,
                              hipStream_t stream) {
    const float* x   = (const float*)d_in[0];
    const float* lnw = (const float*)d_in[1];
    const float* lnb = (const float*)d_in[2];
    const float* W   = (const float*)d_in[3];
    float* out = (float*)d_out;

    unsigned short* Wb = (unsigned short*)d_ws;                        // 294912 B
    float* bias = (float*)((char*)d_ws + (size_t)NOUT * KIN * 2);      // 768 B
    float* Scol = bias + NOUT;                                         // 768 B

    prep_kernel<<<NOUT, 256, 0, stream>>>(W, lnw, lnb, Wb, bias, Scol);
    merge_kernel<<<2048, 256, 0, stream>>>(x, Wb, bias, Scol, out);
}

// Round 3
// 324.116 us; speedup vs baseline: 1.0664x; 1.0664x over previous
//
#include <hip/hip_runtime.h>
#include <stdint.h>

// Problem constants (fixed by the reference)
#define C_IN   96
#define KIN    768      // 8*C
#define NOUT   192
#define MTILE  32       // tokens per block
#define LDK    772      // KIN + 4 bf16 pad (1544 B row stride: odd multiple of 8 B)
#define EPS    1e-5f
#define NKIT   24       // K iterations (768/32)

typedef __bf16 bf16x8 __attribute__((ext_vector_type(8)));
typedef float  f32x4  __attribute__((ext_vector_type(4)));

static __device__ __forceinline__ unsigned int f2bf(float f) {
    union { float f; unsigned int u; } v; v.f = f;
    return (v.u + 0x7fffu + ((v.u >> 16) & 1u)) >> 16;   // RNE bf16, low 16 bits
}
static __device__ __forceinline__ float bf2f(unsigned int s) {
    union { unsigned int u; float f; } v; v.u = s << 16;
    return v.f;
}

// ---------------------------------------------------------------------------
// prep_bias: bias[o] = sum_c ln_b[c]*W[o][c];  Scol[o] = sum_c bf16(W[o][c]*ln_w[c])
// (colsum folds mean subtraction: out = rs*(y_raw.W'^T - mu*S) + bias)
// ---------------------------------------------------------------------------
__global__ __launch_bounds__(256) void prep_bias(
    const float* __restrict__ W, const float* __restrict__ lnw,
    const float* __restrict__ lnb, float* __restrict__ bias,
    float* __restrict__ Scol)
{
    int o = blockIdx.x;
    int tid = threadIdx.x;
    float bpart = 0.f, spart = 0.f;
    for (int c = tid; c < KIN; c += 256) {
        float w = W[(size_t)o * KIN + c];
        spart += bf2f(f2bf(w * lnw[c]));
        bpart += w * lnb[c];
    }
    #pragma unroll
    for (int m = 32; m >= 1; m >>= 1) {
        bpart += __shfl_xor(bpart, m, 64);
        spart += __shfl_xor(spart, m, 64);
    }
    __shared__ float redb[4], reds[4];
    if ((tid & 63) == 0) { redb[tid >> 6] = bpart; reds[tid >> 6] = spart; }
    __syncthreads();
    if (tid == 0) {
        bias[o] = redb[0] + redb[1] + redb[2] + redb[3];
        Scol[o] = reds[0] + reds[1] + reds[2] + reds[3];
    }
}

// ---------------------------------------------------------------------------
// prep_swz: W' in MFMA-B-fragment order. Fragment (nt, kk) is a contiguous
// 1 KB block: lane l holds B[n = nt*16 + (l&15)][k = kk*32 + (l>>4)*8 .. +8].
// Wave B-loads in the merge kernel become fully-coalesced dwordx4 streams.
// ---------------------------------------------------------------------------
__global__ __launch_bounds__(256) void prep_swz(
    const float* __restrict__ W, const float* __restrict__ lnw,
    unsigned short* __restrict__ Wsw)
{
    const int nt = blockIdx.x;               // 0..11
    for (int s = threadIdx.x; s < NKIT * 64; s += 256) {
        const int kk = s >> 6;
        const int l  = s & 63;
        const int row = nt * 16 + (l & 15);
        const int k0  = kk * 32 + (l >> 4) * 8;
        const float* src = W + (size_t)row * KIN + k0;
        unsigned int p[4];
        #pragma unroll
        for (int j = 0; j < 4; ++j) {
            float a = src[2 * j]     * lnw[k0 + 2 * j];
            float b = src[2 * j + 1] * lnw[k0 + 2 * j + 1];
            p[j] = f2bf(a) | (f2bf(b) << 16);
        }
        *(uint4*)&Wsw[(size_t)((nt * NKIT + kk) * 64 + l) * 8] =
            make_uint4(p[0], p[1], p[2], p[3]);
    }
}

// ---------------------------------------------------------------------------
// Fused gather + LayerNorm + GEMM (bf16 MFMA 16x16x32)
// 256 threads (4 waves), 32 tokens, 3 blocks/CU (LDS-limited).
// ---------------------------------------------------------------------------
__global__ __launch_bounds__(256, 3) void merge_kernel(
    const float* __restrict__ x, const unsigned short* __restrict__ Wsw,
    const float* __restrict__ bias, const float* __restrict__ Scol,
    float* __restrict__ out)
{
    __shared__ unsigned short ylds[MTILE * LDK];   // 49408 B
    __shared__ float muL[MTILE], rsL[MTILE];

    const int tid   = threadIdx.x;
    const int tbase = blockIdx.x * MTILE;
    const int bh = blockIdx.x;                 // = (b*32+d)*32 + h
    const int h  = bh & 31;
    const int d  = (bh >> 5) & 31;
    const int b  = bh >> 10;

    // ---- Phase 1: gather fp32 -> regs (ALL loads forced in flight) ----------
    const int tk = tid >> 3;   // token == w coordinate
    const int i  = tid & 7;    // sub-lane: 8 lanes x 16 B = 128 B per voxel run
    const float* base = x +
        ((size_t)((b * 64 + 2 * d) * 64 + 2 * h) * 64 + 2 * tk) * C_IN + i * 4;

    // voxel offsets (floats): (s0*4096 + s1*64 + s2)*96
    const int OFF[8] = {0, 96, 6144, 6240, 393216, 393312, 399360, 399456};

    float4 v[24];
    #pragma unroll
    for (int g = 0; g < 8; ++g)
        #pragma unroll
        for (int jj = 0; jj < 3; ++jj)
            v[g * 3 + jj] = *(const float4*)(base + OFF[g] + jj * 32);

    // Pin the schedule: no consume may be hoisted above, no load sunk below.
    __builtin_amdgcn_sched_barrier(0);

    float sum = 0.f, sq = 0.f;
    #pragma unroll
    for (int g = 0; g < 8; ++g) {
        #pragma unroll
        for (int jj = 0; jj < 3; ++jj) {
            float4 t = v[g * 3 + jj];
            sum += t.x + t.y + t.z + t.w;
            sq  += t.x * t.x + t.y * t.y + t.z * t.z + t.w * t.w;
            uint2 p;
            p.x = f2bf(t.x) | (f2bf(t.y) << 16);
            p.y = f2bf(t.z) | (f2bf(t.w) << 16);
            *(uint2*)&ylds[tk * LDK + g * 96 + (i + jj * 8) * 4] = p;
        }
    }
    #pragma unroll
    for (int m = 4; m >= 1; m >>= 1) {
        sum += __shfl_xor(sum, m, 8);
        sq  += __shfl_xor(sq,  m, 8);
    }
    if (i == 0) {
        float mean = sum * (1.f / 768.f);
        float var  = sq * (1.f / 768.f) - mean * mean;
        muL[tk] = mean;
        rsL[tk] = rsqrtf(var + EPS);
    }
    __syncthreads();

    // ---- Phase 2: GEMM on RAW bf16 y:  C = y . W'^T -------------------------
    // wave wv: N cols [wv*48, wv*48+48) = global n-tiles 3wv..3wv+2
    const int wv    = tid >> 6;
    const int l     = tid & 63;
    const int l15   = l & 15;
    const int quad  = l >> 4;
    const int nbase = wv * 48;
    const int koff  = quad * 8;

    f32x4 acc[2][3];
    #pragma unroll
    for (int mt = 0; mt < 2; ++mt)
        #pragma unroll
        for (int nt = 0; nt < 3; ++nt)
            acc[mt][nt] = (f32x4){0.f, 0.f, 0.f, 0.f};

    const unsigned short* arow0 = &ylds[l15        * LDK + koff];
    const unsigned short* arow1 = &ylds[(16 + l15) * LDK + koff];
    // swizzled B: fragment (nt_g, kk) at ((nt_g*24 + kk)*64 + l)*8, lane-contig
    const unsigned short* bp0 = Wsw + ((size_t)((3 * wv + 0) * NKIT) * 64 + l) * 8;
    const unsigned short* bp1 = Wsw + ((size_t)((3 * wv + 1) * NKIT) * 64 + l) * 8;
    const unsigned short* bp2 = Wsw + ((size_t)((3 * wv + 2) * NKIT) * 64 + l) * 8;

    // depth-2 software pipeline: stage S[kk&1]; loads for kk+2 issued pre-MFMA
    bf16x8 A0[2], A1[2], B0[2], B1[2], B2[2];
    #pragma unroll
    for (int p = 0; p < 2; ++p) {
        A0[p] = *(const bf16x8*)(arow0 + p * 32);
        A1[p] = *(const bf16x8*)(arow1 + p * 32);
        B0[p] = *(const bf16x8*)(bp0 + p * 512);   // 512 bf16 = 1 KB fragment
        B1[p] = *(const bf16x8*)(bp1 + p * 512);
        B2[p] = *(const bf16x8*)(bp2 + p * 512);
    }
    #pragma unroll
    for (int kk = 0; kk < NKIT; ++kk) {
        const int c = kk & 1;
        bf16x8 na0, na1, nb0, nb1, nb2;
        if (kk < NKIT - 2) {
            const int k2 = kk + 2;
            na0 = *(const bf16x8*)(arow0 + k2 * 32);
            na1 = *(const bf16x8*)(arow1 + k2 * 32);
            nb0 = *(const bf16x8*)(bp0 + k2 * 512);
            nb1 = *(const bf16x8*)(bp1 + k2 * 512);
            nb2 = *(const bf16x8*)(bp2 + k2 * 512);
        }
        acc[0][0] = __builtin_amdgcn_mfma_f32_16x16x32_bf16(A0[c], B0[c], acc[0][0], 0, 0, 0);
        acc[0][1] = __builtin_amdgcn_mfma_f32_16x16x32_bf16(A0[c], B1[c], acc[0][1], 0, 0, 0);
        acc[0][2] = __builtin_amdgcn_mfma_f32_16x16x32_bf16(A0[c], B2[c], acc[0][2], 0, 0, 0);
        acc[1][0] = __builtin_amdgcn_mfma_f32_16x16x32_bf16(A1[c], B0[c], acc[1][0], 0, 0, 0);
        acc[1][1] = __builtin_amdgcn_mfma_f32_16x16x32_bf16(A1[c], B1[c], acc[1][1], 0, 0, 0);
        acc[1][2] = __builtin_amdgcn_mfma_f32_16x16x32_bf16(A1[c], B2[c], acc[1][2], 0, 0, 0);
        if (kk < NKIT - 2) {
            A0[c] = na0; A1[c] = na1; B0[c] = nb0; B1[c] = nb1; B2[c] = nb2;
        }
    }

    // ---- Epilogue: out = rs*(dot - mu*S) + bias -----------------------------
    const float S0 = Scol[nbase + l15];
    const float S1 = Scol[nbase + 16 + l15];
    const float S2 = Scol[nbase + 32 + l15];
    const float c0 = bias[nbase + l15];
    const float c1 = bias[nbase + 16 + l15];
    const float c2 = bias[nbase + 32 + l15];
    #pragma unroll
    for (int mt = 0; mt < 2; ++mt) {
        #pragma unroll
        for (int r = 0; r < 4; ++r) {
            const int row = mt * 16 + quad * 4 + r;
            const float rs = rsL[row];
            const float rm = rs * muL[row];
            float* op = out + (size_t)(tbase + row) * NOUT + nbase + l15;
            op[0]  = rs * acc[mt][0][r] - rm * S0 + c0;
            op[16] = rs * acc[mt][1][r] - rm * S1 + c1;
            op[32] = rs * acc[mt][2][r] - rm * S2 + c2;
        }
    }
}

// ---------------------------------------------------------------------------
extern "C" void kernel_launch(void* const* d_in, const int* in_sizes, int n_in,
                              void* d_out, int out_size, void* d_ws, size_t ws_size,
                              hipStream_t stream) {
    const float* x   = (const float*)d_in[0];
    const float* lnw = (const float*)d_in[1];
    const float* lnb = (const float*)d_in[2];
    const float* W   = (const float*)d_in[3];
    float* out = (float*)d_out;

    unsigned short* Wsw = (unsigned short*)d_ws;                       // 294912 B
    float* bias = (float*)((char*)d_ws + (size_t)NOUT * KIN * 2);      // 768 B
    float* Scol = bias + NOUT;                                         // 768 B

    prep_bias<<<NOUT, 256, 0, stream>>>(W, lnw, lnb, bias, Scol);
    prep_swz<<<12, 256, 0, stream>>>(W, lnw, Wsw);
    merge_kernel<<<2048, 256, 0, stream>>>(x, Wsw, bias, Scol, out);
}